// Round 10
// baseline (4257.164 us; speedup 1.0000x reference)
//
#include <hip/hip_runtime.h>
#include <hip/hip_bf16.h>
#include <stdint.h>

// GRU decoder: B=128, IN=256, H=512, SEQ=1024, fp32 out.
// R16 = R12 (incremental sentinel-poll ring, PASSED, 2956us) with HALF the
// sync participants: 16 WGs/bg x 1 wave x 32 output cols (was 32 WGs x 16
// cols). R15's lesson: poll TRAFFIC is not the limiter (halving it regressed
// via coupling); the stall is rounds x MALL-RT + straggler skew. R16 halves
// the straggler population (max over 16 producers, not 32) and halves poll
// issue pressure (128 waves) with ZERO change to the sync skeleton: same
// sentinel ring (depth 8, bf16 pairs, |h|<=1 -> bit14==0, 0xFFFFFFFF
// sentinel), same sc0 sc1 poll loads, same store-inclusive vmcnt(0) before
// validation (R13 lesson: that drain is part of the timing), same ballot
// validation + monotone incremental re-poll, same slot-(s+2) reset, same
// relaxed system-scope publishes, no cross-wave coupling (one wave per WG).
// Per-wave work doubles (96 MFMA + 8-col gates) but sits inside the stall
// window. w_hh fragment LDS doubles to 96KB (6 tiles: 3 gates x 2 col-tiles).

constexpr int SEQ = 1024;
constexpr int BATCH = 128;
constexpr int IND = 256;
constexpr int HD = 512;
constexpr int BG = 8;
constexpr int CG = 16;             // 32-col groups per bg
constexpr int ROWS = BATCH / BG;   // 16
constexpr int NT = 6;              // tiles: {r,z,n} x {ct0,ct1}, t = g*2+ct
constexpr int RING_D = 8;
constexpr int SLOT_DW = BATCH * HD / 2;                      // 32768 dwords
constexpr size_t RING_BYTES = (size_t)RING_D * SLOT_DW * 4;  // 1 MB

using frag16 = __attribute__((ext_vector_type(8))) short;  // 8 bf16
using f32x4  = __attribute__((ext_vector_type(4))) float;
using u32x4  = __attribute__((ext_vector_type(4))) unsigned;

__device__ __forceinline__ float sigmoid_f(float x) {
    return 1.f / (1.f + __expf(-x));
}
__device__ __forceinline__ float tanh_f(float x) {
    float e = __expf(2.f * x);
    return 1.f - 2.f / (e + 1.f);
}
__device__ __forceinline__ short f2bf(float x) {
    return (short)__bfloat16_as_ushort(__float2bfloat16(x));
}

__global__ __launch_bounds__(64, 1) void gru_kernel(
    const float* __restrict__ x,      // [128, 256]
    const float* __restrict__ w_ih,   // [1536, 256]
    const float* __restrict__ w_hh,   // [1536, 512] fp32 (converted here)
    const float* __restrict__ b_ih,   // [1536]
    const float* __restrict__ b_hh,   // [1536]
    unsigned* __restrict__ ring,      // RING_D * [128, 512] bf16, 0xFF-filled
    float* __restrict__ out)          // [128, 1024, 512] fp32
{
    const int lane = threadIdx.x;
    const int bg = blockIdx.x & 7;
    const int cg = blockIdx.x >> 3;   // 0..15
    const int b0 = bg * ROWS;
    const int c0 = cg * 32;
    const int nlo = lane & 15;
    const int quad = lane >> 4;

    // gate-row indices for this lane's six tiles: t = g*2 + ct
    int gcol[NT];
#pragma unroll
    for (int g = 0; g < 3; ++g)
#pragma unroll
        for (int ct = 0; ct < 2; ++ct)
            gcol[g * 2 + ct] = g * HD + c0 + ct * 16 + nlo;

    // ---- stage w_hh slice -> LDS in fragment order (once): 96 KB ----
    __shared__ frag16 ldsB[NT * 16 * 64];
#pragma unroll
    for (int t = 0; t < NT; ++t) {
        for (int kc = 0; kc < 16; ++kc) {
            const float* src = w_hh + (size_t)gcol[t] * HD + kc * 32 + quad * 8;
            float4 v0 = *(const float4*)src;
            float4 v1 = *(const float4*)(src + 4);
            frag16 f;
            f[0] = f2bf(v0.x); f[1] = f2bf(v0.y); f[2] = f2bf(v0.z); f[3] = f2bf(v0.w);
            f[4] = f2bf(v1.x); f[5] = f2bf(v1.y); f[6] = f2bf(v1.z); f[7] = f2bf(v1.w);
            ldsB[(t * 16 + kc) * 64 + lane] = f;
        }
    }

    // ---- gi = x @ w_ih.T + b_ih (+ b_hh folded for r,z) ----
    float gi[NT][4];
    float bhn2[2] = {b_hh[gcol[4]], b_hh[gcol[5]]};
#pragma unroll
    for (int t = 0; t < NT; ++t) {
        float bi = b_ih[gcol[t]] + ((t < 4) ? b_hh[gcol[t]] : 0.f);
#pragma unroll
        for (int r = 0; r < 4; ++r) gi[t][r] = bi;
    }
    for (int r = 0; r < 4; ++r) {
        const float4* xr = (const float4*)(x + (size_t)(b0 + quad * 4 + r) * IND);
        for (int kc = 0; kc < IND / 4; ++kc) {
            float4 xv = xr[kc];
#pragma unroll
            for (int t = 0; t < NT; ++t) {
                float4 wv = ((const float4*)(w_ih + (size_t)gcol[t] * IND))[kc];
                gi[t][r] += xv.x * wv.x + xv.y * wv.y + xv.z * wv.z + xv.w * wv.w;
            }
        }
    }

    // ---- recurrence ----
    // A-fragment source (unchanged from R12: depends on batch rows + K only):
    // lane reads bf16 row (b0+nlo), cols kc*32+quad*8..+8 of slot (s-1)%8.
    const size_t arow_byte = (size_t)(b0 + nlo) * (HD * 2) + quad * 16;

    float hreg[2][4];
#pragma unroll
    for (int ct = 0; ct < 2; ++ct)
#pragma unroll
        for (int r = 0; r < 4; ++r) hreg[ct][r] = 0.f;

    for (int s = 0; s < SEQ; ++s) {
        f32x4 C[NT];
#pragma unroll
        for (int t = 0; t < NT; ++t) C[t] = (f32x4){0.f, 0.f, 0.f, 0.f};

        if (s > 0) {
            const char* lrow =
                (const char*)(ring + ((s - 1) & (RING_D - 1)) * SLOT_DW) + arow_byte;
            u32x4 raw[16];
            // monotone incremental poll (R12-verbatim): re-load only invalid
            // chunks; vmask lane-uniform via ballots -> uniform branches.
            unsigned vmask = 0u;
            do {
#pragma unroll
                for (int kc = 0; kc < 16; ++kc) {
                    if (!(vmask & (1u << kc))) {
                        asm volatile("global_load_dwordx4 %0, %1, off sc0 sc1"
                                     : "=v"(raw[kc]) : "v"(lrow + kc * 64) : "memory");
                    }
                }
                asm volatile("s_waitcnt vmcnt(0)" ::: "memory");
                __builtin_amdgcn_sched_barrier(0);  // validate below the wait
#pragma unroll
                for (int kc = 0; kc < 16; ++kc) {
                    if (!(vmask & (1u << kc))) {
                        // valid bf16 pair: |h|<=1 -> bit14 of each half == 0
                        unsigned orr = raw[kc][0] | raw[kc][1] | raw[kc][2] | raw[kc][3];
                        if (__ballot((orr & 0x40004000u) == 0u) == ~0ull)
                            vmask |= (1u << kc);
                    }
                }
            } while (vmask != 0xFFFFu);
            // MFMA: loaded dwords ARE the bf16 A-fragments (zero converts)
#pragma unroll
            for (int kc = 0; kc < 16; ++kc) {
                union { u32x4 u; frag16 f; } cv;
                cv.u = raw[kc];
#pragma unroll
                for (int t = 0; t < NT; ++t) {
                    frag16 bfr = ldsB[(t * 16 + kc) * 64 + lane];
                    C[t] = __builtin_amdgcn_mfma_f32_16x16x32_bf16(cv.f, bfr, C[t], 0, 0, 0);
                }
            }
        }

        // gates; publish each hn the moment it's ready (R12-verbatim pattern)
        unsigned* wslot = ring + (s & (RING_D - 1)) * SLOT_DW;
        unsigned* rslot = ring + ((s + 2) & (RING_D - 1)) * SLOT_DW;
        float hn[2][4];
#pragma unroll
        for (int ct = 0; ct < 2; ++ct) {
#pragma unroll
            for (int r = 0; r < 4; ++r) {
                float gr  = gi[0 + ct][r] + C[0 + ct][r];
                float gz  = gi[2 + ct][r] + C[2 + ct][r];
                float ghn = C[4 + ct][r] + bhn2[ct];
                float rr = sigmoid_f(gr);
                float zz = sigmoid_f(gz);
                float nn = tanh_f(gi[4 + ct][r] + rr * ghn);
                float h = (1.f - zz) * nn + zz * hreg[ct][r];
                hn[ct][r] = h;
                hreg[ct][r] = h;
                unsigned own = (unsigned)(unsigned short)f2bf(h);
                unsigned other = (unsigned)__shfl_xor((int)own, 1);
                if ((lane & 1) == 0) {
                    int row = b0 + quad * 4 + r;
                    int col = c0 + ct * 16 + nlo;
                    unsigned idx = (unsigned)(row * HD + col) >> 1;
                    __hip_atomic_store(wslot + idx, own | (other << 16),
                                       __ATOMIC_RELAXED, __HIP_MEMORY_SCOPE_SYSTEM);
                }
            }
        }
        // reset own tiles in slot s+2 (sentinel restore; R12-verbatim)
#pragma unroll
        for (int ct = 0; ct < 2; ++ct) {
#pragma unroll
            for (int r = 0; r < 4; ++r) {
                if ((lane & 1) == 0) {
                    int row = b0 + quad * 4 + r;
                    int col = c0 + ct * 16 + nlo;
                    unsigned idx = (unsigned)(row * HD + col) >> 1;
                    __hip_atomic_store(rslot + idx, 0xFFFFFFFFu,
                                       __ATOMIC_RELAXED, __HIP_MEMORY_SCOPE_SYSTEM);
                }
            }
        }
        // out: non-temporal fp32 stream, don't pollute L2/MALL
#pragma unroll
        for (int ct = 0; ct < 2; ++ct) {
#pragma unroll
            for (int r = 0; r < 4; ++r) {
                int row = b0 + quad * 4 + r;
                int col = c0 + ct * 16 + nlo;
                __builtin_nontemporal_store(
                    hn[ct][r],
                    out + (size_t)row * (SEQ * HD) + (size_t)s * HD + col);
            }
        }
    }
}

extern "C" void kernel_launch(void* const* d_in, const int* in_sizes, int n_in,
                              void* d_out, int out_size, void* d_ws, size_t ws_size,
                              hipStream_t stream) {
    (void)in_sizes; (void)n_in; (void)out_size; (void)ws_size;
    const float* x    = (const float*)d_in[0];
    const float* w_ih = (const float*)d_in[1];
    const float* w_hh = (const float*)d_in[2];
    const float* b_ih = (const float*)d_in[3];
    const float* b_hh = (const float*)d_in[4];

    unsigned* ring = (unsigned*)d_ws;  // proven footprint: 1 MB at offset 0
    hipMemsetAsync(ring, 0xFF, RING_BYTES, stream);  // sentinel fill
    gru_kernel<<<BG * CG, 64, 0, stream>>>(x, w_ih, w_hh, b_ih, b_hh, ring,
                                           (float*)d_out);
}